// Round 1
// baseline (5599.937 us; speedup 1.0000x reference)
//
#include <hip/hip_runtime.h>

#define N_NODES 100000
#define N_EDGES 3200000
#define DIM 128

// ---------------- kernel 1: in-degree histogram (int atomics) ----------------
__global__ void __launch_bounds__(256) deg_kernel(const int* __restrict__ dst,
                                                  int* __restrict__ deg) {
    int i = blockIdx.x * 256 + threadIdx.x;
    if (i < N_EDGES) atomicAdd(&deg[dst[i]], 1);
}

// ---------------- kernel 2: norm = rsqrt(max(deg,1)) ----------------
__global__ void __launch_bounds__(256) norm_kernel(const int* __restrict__ deg,
                                                   float* __restrict__ norm) {
    int i = blockIdx.x * 256 + threadIdx.x;
    if (i < N_NODES) norm[i] = rsqrtf(fmaxf((float)deg[i], 1.0f));
}

// ---------------- kernel 3: edge scatter: out[dst] += feat[src]*norm[src] ----
// 32 lanes per edge, each lane handles a float4 (16B) of the 512B row.
__global__ void __launch_bounds__(256) scatter_kernel(
        const float* __restrict__ feat, const float* __restrict__ norm,
        const int* __restrict__ src, const int* __restrict__ dst,
        float* __restrict__ agg) {
    const int lane = threadIdx.x & 31;
    const int e = blockIdx.x * 8 + (threadIdx.x >> 5);
    if (e >= N_EDGES) return;
    const int s = src[e];
    const int d = dst[e];
    const float ns = norm[s];
    float4 v = reinterpret_cast<const float4*>(feat + (size_t)s * DIM)[lane];
    float* o = agg + (size_t)d * DIM + lane * 4;
    unsafeAtomicAdd(o + 0, v.x * ns);
    unsafeAtomicAdd(o + 1, v.y * ns);
    unsafeAtomicAdd(o + 2, v.z * ns);
    unsafeAtomicAdd(o + 3, v.w * ns);
}

// ---------------- kernel 4: out = relu(norm[i] * (agg @ W^T)) + feat --------
// In-place on the agg buffer (= d_out). W^T staged in LDS (transposed so
// lane-consecutive 'o' reads are bank-conflict-free); 8 rows per block-iter,
// 4-row register blocking to amortize the W read.
__global__ void __launch_bounds__(256) final_kernel(
        const float* __restrict__ feat, const float* __restrict__ W,
        const float* __restrict__ norm, float* __restrict__ out) {
    __shared__ float Wt[DIM * DIM];      // Wt[k*128+o] = W[o*128+k]  (64 KB)
    __shared__ float rowbuf[8][DIM];     // 4 KB
    for (int idx = threadIdx.x; idx < DIM * DIM; idx += 256) {
        // write conflict-free (consecutive idx), read strided (L2-served, one-time)
        Wt[idx] = W[(idx & 127) * DIM + (idx >> 7)];
    }
    const int o  = threadIdx.x & 127;
    const int r0 = (threadIdx.x >> 7) * 4;   // 0 or 4

    for (int rb = blockIdx.x * 8; rb < N_NODES; rb += gridDim.x * 8) {
        __syncthreads();   // covers Wt staging (iter 0) and rowbuf reuse (iters >0)
        // stage rows rb..rb+7 (8*128 floats = 256 float4, one per thread)
        float4 v = reinterpret_cast<const float4*>(out + (size_t)rb * DIM)[threadIdx.x];
        reinterpret_cast<float4*>(&rowbuf[0][0])[threadIdx.x] = v;
        __syncthreads();

        float acc0 = 0.f, acc1 = 0.f, acc2 = 0.f, acc3 = 0.f;
        #pragma unroll 8
        for (int k = 0; k < DIM; ++k) {
            float w = Wt[k * DIM + o];                 // 2-way (free) bank access
            acc0 = fmaf(rowbuf[r0 + 0][k], w, acc0);   // uniform-address broadcasts
            acc1 = fmaf(rowbuf[r0 + 1][k], w, acc1);
            acc2 = fmaf(rowbuf[r0 + 2][k], w, acc2);
            acc3 = fmaf(rowbuf[r0 + 3][k], w, acc3);
        }
        float accs[4] = {acc0, acc1, acc2, acc3};
        #pragma unroll
        for (int r = 0; r < 4; ++r) {
            int row = rb + r0 + r;
            float val = fmaxf(accs[r] * norm[row], 0.0f) + feat[(size_t)row * DIM + o];
            out[(size_t)row * DIM + o] = val;
        }
    }
}

extern "C" void kernel_launch(void* const* d_in, const int* in_sizes, int n_in,
                              void* d_out, int out_size, void* d_ws, size_t ws_size,
                              hipStream_t stream) {
    const float* feat = (const float*)d_in[0];
    const float* W    = (const float*)d_in[1];
    const int*   src  = (const int*)d_in[2];
    const int*   dst  = (const int*)d_in[3];
    float* out  = (float*)d_out;
    int*   deg  = (int*)d_ws;                       // 400 KB
    float* norm = (float*)d_ws + N_NODES;           // 400 KB

    // zero accumulators every call (harness does not re-poison between replays)
    hipMemsetAsync(d_out, 0, (size_t)N_NODES * DIM * sizeof(float), stream);
    hipMemsetAsync(deg, 0, (size_t)N_NODES * sizeof(int), stream);

    deg_kernel   <<<N_EDGES / 256, 256, 0, stream>>>(dst, deg);
    norm_kernel  <<<(N_NODES + 255) / 256, 256, 0, stream>>>(deg, norm);
    scatter_kernel<<<N_EDGES / 8, 256, 0, stream>>>(feat, norm, src, dst, out);
    final_kernel <<<512, 256, 0, stream>>>(feat, W, norm, out);
}

// Round 2
// 778.388 us; speedup vs baseline: 7.1943x; 7.1943x over previous
//
#include <hip/hip_runtime.h>

#define N_NODES 100000
#define N_EDGES 3200000
#define DIM 128
#define SCAN_B 1024
#define N_SCANB ((N_NODES + SCAN_B - 1) / SCAN_B)   // 98

// ---------------- kernel 1: in-degree histogram (int atomics) ----------------
__global__ void __launch_bounds__(256) deg_kernel(const int* __restrict__ dst,
                                                  int* __restrict__ deg) {
    int i = blockIdx.x * 256 + threadIdx.x;
    if (i < N_EDGES) atomicAdd(&deg[dst[i]], 1);
}

// ---------------- scan pass 1: per-block exclusive scan of deg ---------------
__global__ void __launch_bounds__(SCAN_B) scan1_kernel(const int* __restrict__ deg,
                                                       int* __restrict__ excl,
                                                       int* __restrict__ partials) {
    __shared__ int buf[SCAN_B];
    const int gid = blockIdx.x * SCAN_B + threadIdx.x;
    const int v = (gid < N_NODES) ? deg[gid] : 0;
    buf[threadIdx.x] = v;
    __syncthreads();
    #pragma unroll
    for (int off = 1; off < SCAN_B; off <<= 1) {
        int t = (threadIdx.x >= off) ? buf[threadIdx.x - off] : 0;
        __syncthreads();
        buf[threadIdx.x] += t;
        __syncthreads();
    }
    if (gid < N_NODES) excl[gid] = buf[threadIdx.x] - v;
    if (threadIdx.x == SCAN_B - 1) partials[blockIdx.x] = buf[threadIdx.x];
}

// ---------------- scan pass 2: exclusive scan of the 98 block totals ---------
__global__ void __launch_bounds__(128) scan2_kernel(int* __restrict__ partials) {
    __shared__ int buf[128];
    const int v = (threadIdx.x < N_SCANB) ? partials[threadIdx.x] : 0;
    buf[threadIdx.x] = v;
    __syncthreads();
    #pragma unroll
    for (int off = 1; off < 128; off <<= 1) {
        int t = (threadIdx.x >= off) ? buf[threadIdx.x - off] : 0;
        __syncthreads();
        buf[threadIdx.x] += t;
        __syncthreads();
    }
    if (threadIdx.x < N_SCANB) partials[threadIdx.x] = buf[threadIdx.x] - v;
}

// ---------------- scan pass 3: finalize row_start/cursor + norm --------------
__global__ void __launch_bounds__(SCAN_B) scan3_kernel(
        const int* __restrict__ excl, const int* __restrict__ partials,
        const int* __restrict__ deg,
        int* __restrict__ row_start, int* __restrict__ cursor,
        float* __restrict__ norm) {
    const int gid = blockIdx.x * SCAN_B + threadIdx.x;
    if (gid < N_NODES) {
        const int rs = excl[gid] + partials[blockIdx.x];
        row_start[gid] = rs;
        cursor[gid] = rs;
        norm[gid] = rsqrtf(fmaxf((float)deg[gid], 1.0f));
    }
    if (gid == 0) row_start[N_NODES] = N_EDGES;
}

// ---------------- CSR fill: bucket src ids by dst (int atomics only) ---------
__global__ void __launch_bounds__(256) fill_kernel(
        const int* __restrict__ src, const int* __restrict__ dst,
        int* __restrict__ cursor, int* __restrict__ csr) {
    int i = blockIdx.x * 256 + threadIdx.x;
    if (i < N_EDGES) {
        int pos = atomicAdd(&cursor[dst[i]], 1);
        csr[pos] = src[i];
    }
}

// ---------------- gather: out[n] = sum_{e in CSR[n]} feat[src_e]*norm[src_e] -
// One 64-lane wave per node; lane owns a float2 (8B) slice of the 128-dim row.
// Per edge: 64 lanes x 8B = 512B coalesced read of feat row (L3-resident).
__global__ void __launch_bounds__(256) gather_kernel(
        const float* __restrict__ feat, const float* __restrict__ norm,
        const int* __restrict__ row_start, const int* __restrict__ csr,
        float* __restrict__ out) {
    const int n = blockIdx.x * 4 + (threadIdx.x >> 6);
    if (n >= N_NODES) return;
    const int lane = threadIdx.x & 63;
    const int beg = row_start[n];
    const int end = row_start[n + 1];
    float2 acc = make_float2(0.f, 0.f);
    int e = beg;
    // 2-edge unroll: two independent in-flight loads to hide L2/L3 latency
    for (; e + 1 < end; e += 2) {
        const int s0 = csr[e], s1 = csr[e + 1];
        const float w0 = norm[s0], w1 = norm[s1];
        const float2 v0 = reinterpret_cast<const float2*>(feat + (size_t)s0 * DIM)[lane];
        const float2 v1 = reinterpret_cast<const float2*>(feat + (size_t)s1 * DIM)[lane];
        acc.x = fmaf(v0.x, w0, acc.x); acc.y = fmaf(v0.y, w0, acc.y);
        acc.x = fmaf(v1.x, w1, acc.x); acc.y = fmaf(v1.y, w1, acc.y);
    }
    if (e < end) {
        const int s0 = csr[e];
        const float w0 = norm[s0];
        const float2 v0 = reinterpret_cast<const float2*>(feat + (size_t)s0 * DIM)[lane];
        acc.x = fmaf(v0.x, w0, acc.x); acc.y = fmaf(v0.y, w0, acc.y);
    }
    reinterpret_cast<float2*>(out + (size_t)n * DIM)[lane] = acc;
}

// ---------------- final: out = relu(norm[i] * (out @ W^T)) + feat ------------
__global__ void __launch_bounds__(256) final_kernel(
        const float* __restrict__ feat, const float* __restrict__ W,
        const float* __restrict__ norm, float* __restrict__ out) {
    __shared__ float Wt[DIM * DIM];      // Wt[k*128+o] = W[o*128+k]  (64 KB)
    __shared__ float rowbuf[8][DIM];     // 4 KB
    for (int idx = threadIdx.x; idx < DIM * DIM; idx += 256) {
        Wt[idx] = W[(idx & 127) * DIM + (idx >> 7)];
    }
    const int o  = threadIdx.x & 127;
    const int r0 = (threadIdx.x >> 7) * 4;   // 0 or 4

    for (int rb = blockIdx.x * 8; rb < N_NODES; rb += gridDim.x * 8) {
        __syncthreads();   // covers Wt staging (iter 0) and rowbuf reuse (iters >0)
        float4 v = reinterpret_cast<const float4*>(out + (size_t)rb * DIM)[threadIdx.x];
        reinterpret_cast<float4*>(&rowbuf[0][0])[threadIdx.x] = v;
        __syncthreads();

        float acc0 = 0.f, acc1 = 0.f, acc2 = 0.f, acc3 = 0.f;
        #pragma unroll 8
        for (int k = 0; k < DIM; ++k) {
            float w = Wt[k * DIM + o];                 // 2-way (free) bank access
            acc0 = fmaf(rowbuf[r0 + 0][k], w, acc0);   // uniform-address broadcasts
            acc1 = fmaf(rowbuf[r0 + 1][k], w, acc1);
            acc2 = fmaf(rowbuf[r0 + 2][k], w, acc2);
            acc3 = fmaf(rowbuf[r0 + 3][k], w, acc3);
        }
        float accs[4] = {acc0, acc1, acc2, acc3};
        #pragma unroll
        for (int r = 0; r < 4; ++r) {
            int row = rb + r0 + r;
            float val = fmaxf(accs[r] * norm[row], 0.0f) + feat[(size_t)row * DIM + o];
            out[(size_t)row * DIM + o] = val;
        }
    }
}

extern "C" void kernel_launch(void* const* d_in, const int* in_sizes, int n_in,
                              void* d_out, int out_size, void* d_ws, size_t ws_size,
                              hipStream_t stream) {
    const float* feat = (const float*)d_in[0];
    const float* W    = (const float*)d_in[1];
    const int*   src  = (const int*)d_in[2];
    const int*   dst  = (const int*)d_in[3];
    float* out = (float*)d_out;

    // workspace layout (~14.8 MB)
    char* ws = (char*)d_ws;
    int*   deg       = (int*)ws;                 ws += N_NODES * sizeof(int);
    int*   excl      = (int*)ws;                 ws += N_NODES * sizeof(int);
    int*   cursor    = (int*)ws;                 ws += N_NODES * sizeof(int);
    int*   row_start = (int*)ws;                 ws += (N_NODES + 1) * sizeof(int);
    float* norm      = (float*)ws;               ws += N_NODES * sizeof(float);
    int*   partials  = (int*)ws;                 ws += 128 * sizeof(int);
    int*   csr       = (int*)ws;                 // 12.8 MB

    hipMemsetAsync(deg, 0, (size_t)N_NODES * sizeof(int), stream);

    deg_kernel  <<<N_EDGES / 256, 256, 0, stream>>>(dst, deg);
    scan1_kernel<<<N_SCANB, SCAN_B, 0, stream>>>(deg, excl, partials);
    scan2_kernel<<<1, 128, 0, stream>>>(partials);
    scan3_kernel<<<N_SCANB, SCAN_B, 0, stream>>>(excl, partials, deg,
                                                 row_start, cursor, norm);
    fill_kernel <<<N_EDGES / 256, 256, 0, stream>>>(src, dst, cursor, csr);
    gather_kernel<<<(N_NODES + 3) / 4, 256, 0, stream>>>(feat, norm, row_start, csr, out);
    final_kernel<<<512, 256, 0, stream>>>(feat, W, norm, out);
}